// Round 1
// baseline (145.967 us; speedup 1.0000x reference)
//
#include <hip/hip_runtime.h>

// out[i_local, j] = dis2  if (j > i) & neighbor-voxel & (dis2 < sum_radii_sq) & (ri < 1)
//                 = 0     otherwise
// where i = start_idx + i_local.
//
// Equivalence to the reference's hash test: valid requires dis2 < srs <= 0.49
// for this radii range, which forces |ci - cj| <= 1 per axis (voxel size 1.0),
// under which the 27-neighbor hash membership is exactly true. Hash collisions
// only ever add pairs that fail the distance test, so the outputs are identical.
//
// All float ops use explicit _rn intrinsics with the reference's association
// ((dx^2 + dy^2) + dz^2) so the dis2 < srs comparison is bit-exact vs numpy.

__global__ __launch_bounds__(256) void pair_dist_kernel(
    const float* __restrict__ pts,   // (n,3) fp32
    const float* __restrict__ rad,   // (n,)  fp32
    const int*  __restrict__ start_ptr,
    float* __restrict__ out,         // (chunk, n) fp32
    int n)
{
    const int start   = *start_ptr;            // scalar (wave-uniform) load
    const int i_local = blockIdx.y;
    const int i       = start + i_local;

    // Row point/radius — uniform per block, compiler emits scalar loads.
    const float xi = pts[i * 3 + 0];
    const float yi = pts[i * 3 + 1];
    const float zi = pts[i * 3 + 2];
    const float ri = rad[i];
    const int   cix = (int)xi, ciy = (int)yi, ciz = (int)zi;
    const bool  ri_ok = ri < 1.0f;             // DIS_THRESHOLD

    const int tcol = blockIdx.x * 256 + threadIdx.x;   // float4 column index
    const int j0   = tcol * 4;

    // 4 consecutive points = 12 contiguous floats, 16B-aligned (j0 % 4 == 0).
    const float4* p4 = (const float4*)(pts + (size_t)j0 * 3);
    const float4 a = p4[0];
    const float4 b = p4[1];
    const float4 c = p4[2];
    const float px[4] = {a.x, a.w, b.z, c.y};
    const float py[4] = {a.y, b.x, b.w, c.z};
    const float pz[4] = {a.z, b.y, c.x, c.w};

    const float4 r4 = *(const float4*)(rad + j0);
    const float rj[4] = {r4.x, r4.y, r4.z, r4.w};

    float4 res;
    float* resp = &res.x;
    #pragma unroll
    for (int k = 0; k < 4; ++k) {
        const int j = j0 + k;

        const float dx = __fsub_rn(xi, px[k]);
        const float dy = __fsub_rn(yi, py[k]);
        const float dz = __fsub_rn(zi, pz[k]);
        const float d2 = __fadd_rn(__fadd_rn(__fmul_rn(dx, dx),
                                             __fmul_rn(dy, dy)),
                                   __fmul_rn(dz, dz));

        const float rjk   = rj[k];
        const float minr  = fminf(ri, rjk);
        const float max_r = __fmul_rn(minr, 1.5f);
        const float s     = __fadd_rn(fminf(ri, max_r), fminf(rjk, max_r));
        const float srs   = __fmul_rn(s, s);   // EDGE_DIST_SCALE == 1.0

        const int cjx = (int)px[k];
        const int cjy = (int)py[k];
        const int cjz = (int)pz[k];
        const bool nb = (abs(cix - cjx) <= 1) &&
                        (abs(ciy - cjy) <= 1) &&
                        (abs(ciz - cjz) <= 1);

        const bool valid = (j > i) && nb && (d2 < srs) && ri_ok;
        resp[k] = valid ? d2 : 0.0f;
    }

    // Coalesced float4 store: row i_local, columns [j0, j0+4).
    ((float4*)out)[(size_t)i_local * (size_t)(n >> 2) + tcol] = res;
}

extern "C" void kernel_launch(void* const* d_in, const int* in_sizes, int n_in,
                              void* d_out, int out_size, void* d_ws, size_t ws_size,
                              hipStream_t stream)
{
    const float* pts = (const float*)d_in[0];   // (n,3)
    const float* rad = (const float*)d_in[1];   // (n,1)
    const int* start_ptr = (const int*)d_in[2]; // scalar on device
    // d_in[3] = end_idx (unused; chunk derived from out_size)

    const int n     = in_sizes[0] / 3;          // 16384
    const int chunk = out_size / n;             // 2048

    dim3 grid(n / (256 * 4), chunk);            // (16, 2048)
    dim3 block(256);
    pair_dist_kernel<<<grid, block, 0, stream>>>(
        pts, rad, start_ptr, (float*)d_out, n);
}

// Round 2
// 142.695 us; speedup vs baseline: 1.0229x; 1.0229x over previous
//
#include <hip/hip_runtime.h>

// out[i_local, j] = dis2  if (j > i) & neighbor-voxel & (dis2 < sum_radii_sq) & (ri < 1)
//                 = 0     otherwise,  i = start_idx + i_local.
//
// Voxel-equivalence: valid requires dis2 < srs <= 0.49, which forces
// |ci - cj| <= 1 per axis (voxel 1.0), under which 27-neighbor hash
// membership is exactly true; hash collisions only add pairs that fail the
// distance test. Bit-exact vs numpy via _rn ops with ((dx2+dy2)+dz2).
//
// R1: 8 rows per block — j-side loads (48B pts + 16B rad) and voxel cvts
// amortized over 8 rows; one coalesced float4 store per row per thread.

#define ROWS 8

__global__ __launch_bounds__(256) void pair_dist_kernel(
    const float* __restrict__ pts,   // (n,3) fp32
    const float* __restrict__ rad,   // (n,)  fp32
    const int*  __restrict__ start_ptr,
    float* __restrict__ out,         // (chunk, n) fp32
    int n)
{
    const int start = *start_ptr;                      // wave-uniform
    const int row0  = blockIdx.y * ROWS;               // i_local base
    const int tcol  = blockIdx.x * 256 + threadIdx.x;  // float4 column index
    const int j0    = tcol * 4;

    // ---- j-side data: loaded once, reused for all ROWS rows ----
    const float4* p4 = (const float4*)(pts + (size_t)j0 * 3);
    const float4 a = p4[0];
    const float4 b = p4[1];
    const float4 c = p4[2];
    const float pjx[4] = {a.x, a.w, b.z, c.y};
    const float pjy[4] = {a.y, b.x, b.w, c.z};
    const float pjz[4] = {a.z, b.y, c.x, c.w};

    const float4 r4 = *(const float4*)(rad + j0);
    const float rj[4] = {r4.x, r4.y, r4.z, r4.w};

    int cjx[4], cjy[4], cjz[4];
    #pragma unroll
    for (int k = 0; k < 4; ++k) {
        cjx[k] = (int)pjx[k];
        cjy[k] = (int)pjy[k];
        cjz[k] = (int)pjz[k];
    }

    // ---- i-side row scalars: uniform per block -> scalar loads ----
    float xi[ROWS], yi[ROWS], zi[ROWS], ri[ROWS];
    #pragma unroll
    for (int r = 0; r < ROWS; ++r) {
        const int i = start + row0 + r;
        xi[r] = pts[i * 3 + 0];
        yi[r] = pts[i * 3 + 1];
        zi[r] = pts[i * 3 + 2];
        ri[r] = rad[i];
    }

    const size_t row_pitch = (size_t)(n >> 2);
    #pragma unroll
    for (int r = 0; r < ROWS; ++r) {
        const int   il  = row0 + r;
        const int   i   = start + il;
        const float x   = xi[r], y = yi[r], z = zi[r], rri = ri[r];
        const int   cix = (int)x, ciy = (int)y, ciz = (int)z;
        const bool  ri_ok = rri < 1.0f;                // DIS_THRESHOLD

        float o0, o1, o2, o3;
        #pragma unroll
        for (int k = 0; k < 4; ++k) {
            const int j = j0 + k;

            const float dx = __fsub_rn(x, pjx[k]);
            const float dy = __fsub_rn(y, pjy[k]);
            const float dz = __fsub_rn(z, pjz[k]);
            const float d2 = __fadd_rn(__fadd_rn(__fmul_rn(dx, dx),
                                                 __fmul_rn(dy, dy)),
                                       __fmul_rn(dz, dz));

            const float rjk   = rj[k];
            const float minr  = fminf(rri, rjk);
            const float max_r = __fmul_rn(minr, 1.5f);
            const float s     = __fadd_rn(fminf(rri, max_r), fminf(rjk, max_r));
            const float srs   = __fmul_rn(s, s);       // EDGE_DIST_SCALE == 1

            // |ci - cj| <= 1  via unsigned trick: (u32)(d + 1) <= 2
            const bool nb = ((unsigned)(cix - cjx[k] + 1) <= 2u) &&
                            ((unsigned)(ciy - cjy[k] + 1) <= 2u) &&
                            ((unsigned)(ciz - cjz[k] + 1) <= 2u);

            const bool valid = (j > i) && nb && (d2 < srs) && ri_ok;
            const float v = valid ? d2 : 0.0f;
            if (k == 0) o0 = v; else if (k == 1) o1 = v;
            else if (k == 2) o2 = v; else o3 = v;
        }

        float4 res = make_float4(o0, o1, o2, o3);
        ((float4*)out)[(size_t)il * row_pitch + tcol] = res;
    }
}

extern "C" void kernel_launch(void* const* d_in, const int* in_sizes, int n_in,
                              void* d_out, int out_size, void* d_ws, size_t ws_size,
                              hipStream_t stream)
{
    const float* pts = (const float*)d_in[0];   // (n,3)
    const float* rad = (const float*)d_in[1];   // (n,1)
    const int* start_ptr = (const int*)d_in[2]; // scalar on device
    // d_in[3] = end_idx (unused; chunk derived from out_size)

    const int n     = in_sizes[0] / 3;          // 16384
    const int chunk = out_size / n;             // 2048

    dim3 grid(n / (256 * 4), chunk / ROWS);     // (16, 256)
    dim3 block(256);
    pair_dist_kernel<<<grid, block, 0, stream>>>(
        pts, rad, start_ptr, (float*)d_out, n);
}